// Round 9
// baseline (118.751 us; speedup 1.0000x reference)
//
#include <hip/hip_runtime.h>

// PmLIF membrane recurrence, T timesteps, state in registers.
// Bit-exact vs the reference f32 op order:
//   t = x - v                      (one rounding; == -(v-0)+x )
//   h = v + inv_tau * t            (mul rounded, add rounded — NO fma fusion)
//   s = (h - v_th) > 0 ? 1 : 0
//   v = s ? 0 : h                  (v_reset = 0; select is exact)
//
// R9: simplest max-occupancy form. f32x2 lanes exactly fill 32 waves/CU
// (2048 blocks x 256 thr, __launch_bounds__(256,8) caps VGPR at 64).
// Flat full unroll — no manual ring/double-buffer; the compiler hoists
// loads to the VGPR budget and schedules the interleave. nt on both
// streams (zero reuse). A/B vs R6's manual ring (102.2 us): tests whether
// manual pipelining was overhead or neutral.

constexpr int T_STEPS = 64;

typedef float f32x2 __attribute__((ext_vector_type(2)));

struct StepOut { float v; float s; };

__device__ __forceinline__ StepOut pmlif_step(float xv, float v,
                                              float inv_tau, float v_th) {
    const float t = __fsub_rn(xv, v);
    const float h = __fadd_rn(v, __fmul_rn(inv_tau, t));
    const float u = __fsub_rn(h, v_th);
    const bool  b = u > 0.0f;
    StepOut r;
    r.s = b ? 1.0f : 0.0f;
    r.v = b ? 0.0f : h;
    return r;
}

__global__ __launch_bounds__(256, 8) void pmlif_scan_kernel(
    const f32x2* __restrict__ x,       // [T][n2]
    f32x2* __restrict__ out,           // [T][n2]
    const float* __restrict__ v_th_p,  // scalar
    const float* __restrict__ tau_p,   // scalar
    int n2)                            // (B*N)/2
{
    const int idx = blockIdx.x * blockDim.x + threadIdx.x;
    if (idx >= n2) return;

    const float v_th    = *v_th_p;
    const float inv_tau = __fdiv_rn(1.0f, *tau_p);

    const f32x2* __restrict__ xp = x + idx;
    f32x2* __restrict__ op = out + idx;
    const size_t step = (size_t)n2;

    float v0 = 0.f, v1 = 0.f;

#pragma unroll
    for (int t = 0; t < T_STEPS; ++t) {
        const f32x2 xv = __builtin_nontemporal_load(&xp[(size_t)t * step]);
        const StepOut r0 = pmlif_step(xv.x, v0, inv_tau, v_th);
        const StepOut r1 = pmlif_step(xv.y, v1, inv_tau, v_th);
        v0 = r0.v; v1 = r1.v;
        f32x2 s; s.x = r0.s; s.y = r1.s;
        __builtin_nontemporal_store(s, &op[(size_t)t * step]);
    }
}

extern "C" void kernel_launch(void* const* d_in, const int* in_sizes, int n_in,
                              void* d_out, int out_size, void* d_ws, size_t ws_size,
                              hipStream_t stream) {
    const float* x    = (const float*)d_in[0];
    const float* v_th = (const float*)d_in[1];
    const float* tau  = (const float*)d_in[2];
    float* out = (float*)d_out;

    const int total = in_sizes[0];            // T * B * N
    const int bn    = total / T_STEPS;        // B * N (inner, contiguous)
    const int n2    = bn / 2;                 // float2 granularity

    const int block = 256;
    const int grid  = (n2 + block - 1) / block;

    pmlif_scan_kernel<<<grid, block, 0, stream>>>(
        (const f32x2*)x, (f32x2*)out, v_th, tau, n2);
}

// Round 10
// 104.661 us; speedup vs baseline: 1.1346x; 1.1346x over previous
//
#include <hip/hip_runtime.h>

// PmLIF membrane recurrence, T timesteps, state in registers.
// Bit-exact vs the reference f32 op order:
//   t = x - v                      (one rounding; == -(v-0)+x )
//   h = v + inv_tau * t            (mul rounded, add rounded — NO fma fusion)
//   s = (h - v_th) > 0 ? 1 : 0
//   v = s ? 0 : h                  (v_reset = 0; select is exact)
//
// R10: exact R6 structure (f32x2, 32 waves/CU, ring PF=8, nt LOADS) with a
// single change: PLAIN stores (write-back through L2) instead of nt stores.
// Rationale: harness fill kernels hit 7.0 TB/s write-only via L2; nt stores
// bypass L2's elastic write buffering and may serialize on the HBM write
// queue. Single-variable A/B vs R6's 102.2 us.

constexpr int T_STEPS = 64;
constexpr int PF      = 8;           // prefetch depth == inner unroll
constexpr int NGRP    = T_STEPS / PF;

typedef float f32x2 __attribute__((ext_vector_type(2)));

struct StepOut { float v; float s; };

__device__ __forceinline__ StepOut pmlif_step(float xv, float v,
                                              float inv_tau, float v_th) {
    const float t = __fsub_rn(xv, v);
    const float h = __fadd_rn(v, __fmul_rn(inv_tau, t));
    const float u = __fsub_rn(h, v_th);
    const bool  b = u > 0.0f;
    StepOut r;
    r.s = b ? 1.0f : 0.0f;
    r.v = b ? 0.0f : h;
    return r;
}

__global__ __launch_bounds__(256, 8) void pmlif_scan_kernel(
    const f32x2* __restrict__ x,       // [T][n2]
    f32x2* __restrict__ out,           // [T][n2]
    const float* __restrict__ v_th_p,  // scalar
    const float* __restrict__ tau_p,   // scalar
    int n2)                            // (B*N)/2
{
    const int idx = blockIdx.x * blockDim.x + threadIdx.x;
    if (idx >= n2) return;

    const float v_th    = *v_th_p;
    const float inv_tau = __fdiv_rn(1.0f, *tau_p);

    const f32x2* __restrict__ xp = x + idx;
    f32x2* __restrict__ op = out + idx;
    const size_t step = (size_t)n2;

    // prologue: fill the ring
    f32x2 buf[PF];
#pragma unroll
    for (int k = 0; k < PF; ++k)
        buf[k] = __builtin_nontemporal_load(&xp[(size_t)k * step]);

    float v0 = 0.f, v1 = 0.f;

    // main: groups 0..NGRP-2 prefetch the next group
    for (int g = 0; g < NGRP - 1; ++g) {
        const f32x2* __restrict__ xg = xp + (size_t)(g + 1) * PF * step;
        f32x2* __restrict__ og = op + (size_t)g * PF * step;
#pragma unroll
        for (int k = 0; k < PF; ++k) {
            const f32x2 xv = buf[k];
            buf[k] = __builtin_nontemporal_load(&xg[(size_t)k * step]);
            const StepOut r0 = pmlif_step(xv.x, v0, inv_tau, v_th);
            const StepOut r1 = pmlif_step(xv.y, v1, inv_tau, v_th);
            v0 = r0.v; v1 = r1.v;
            f32x2 s; s.x = r0.s; s.y = r1.s;
            og[(size_t)k * step] = s;          // plain store (through L2)
        }
    }

    // tail group: no prefetch
    {
        f32x2* __restrict__ og = op + (size_t)(NGRP - 1) * PF * step;
#pragma unroll
        for (int k = 0; k < PF; ++k) {
            const f32x2 xv = buf[k];
            const StepOut r0 = pmlif_step(xv.x, v0, inv_tau, v_th);
            const StepOut r1 = pmlif_step(xv.y, v1, inv_tau, v_th);
            v0 = r0.v; v1 = r1.v;
            f32x2 s; s.x = r0.s; s.y = r1.s;
            og[(size_t)k * step] = s;          // plain store (through L2)
        }
    }
}

extern "C" void kernel_launch(void* const* d_in, const int* in_sizes, int n_in,
                              void* d_out, int out_size, void* d_ws, size_t ws_size,
                              hipStream_t stream) {
    const float* x    = (const float*)d_in[0];
    const float* v_th = (const float*)d_in[1];
    const float* tau  = (const float*)d_in[2];
    float* out = (float*)d_out;

    const int total = in_sizes[0];            // T * B * N
    const int bn    = total / T_STEPS;        // B * N (inner, contiguous)
    const int n2    = bn / 2;                 // float2 granularity

    const int block = 256;
    const int grid  = (n2 + block - 1) / block;

    pmlif_scan_kernel<<<grid, block, 0, stream>>>(
        (const f32x2*)x, (f32x2*)out, v_th, tau, n2);
}

// Round 11
// 104.092 us; speedup vs baseline: 1.1408x; 1.0055x over previous
//
#include <hip/hip_runtime.h>

// PmLIF membrane recurrence, T timesteps, state in registers.
// Bit-exact vs the reference f32 op order (per-site chain unchanged):
//   t = x - v ; h = v + inv_tau*t (rounded mul+add, no fma)
//   s = (h - v_th) > 0 ; v = s ? 0 : h
//
// R11: lane-pair cooperative 16B VMEM at full occupancy.
// Lanes l (even) / l^1 (odd) own adjacent f32x2 sites; together they cover
// one f32x4 (16B) column. Per row-PAIR p: even lane loads 16B of row 2p,
// odd lane loads 16B of row 2p+1 (one load instr per thread per 2 rows);
// an 8B shfl_xor swap gives each lane its half of the other row. Spikes are
// swapped the same way and stored as one 16B instr per thread per 2 rows.
// => VMEM instruction count HALVED at identical occupancy (32 waves/CU),
// bytes identical. Tests the per-VMEM-instruction-overhead theory for the
// 5.0 vs 6.29 TB/s gap. Ring PF=4 pairs = 8 rows of prefetch slack (as R6).

constexpr int T_STEPS = 64;
constexpr int NPAIR   = T_STEPS / 2;  // 32 row-pairs
constexpr int PF      = 4;            // ring depth in pairs (8 rows slack)
constexpr int NGRP    = NPAIR / PF;   // 8 groups

typedef float f32x2 __attribute__((ext_vector_type(2)));
typedef float f32x4 __attribute__((ext_vector_type(4)));

struct StepOut { float v; float s; };

__device__ __forceinline__ StepOut pmlif_step(float xv, float v,
                                              float inv_tau, float v_th) {
    const float t = __fsub_rn(xv, v);
    const float h = __fadd_rn(v, __fmul_rn(inv_tau, t));
    const float u = __fsub_rn(h, v_th);
    const bool  b = u > 0.0f;
    StepOut r;
    r.s = b ? 1.0f : 0.0f;
    r.v = b ? 0.0f : h;
    return r;
}

__global__ __launch_bounds__(256, 8) void pmlif_scan_kernel(
    const float* __restrict__ x,       // [T][bn] f32
    float* __restrict__ out,           // [T][bn] f32
    const float* __restrict__ v_th_p,
    const float* __restrict__ tau_p,
    int bn)                            // B*N floats per row
{
    const int idx2 = blockIdx.x * blockDim.x + threadIdx.x;  // f32x2 site id
    const int n2   = bn >> 1;
    if (idx2 >= n2) return;

    const int  q4  = idx2 >> 1;            // shared f32x4 column
    const bool odd = (threadIdx.x & 1);

    const float v_th    = *v_th_p;
    const float inv_tau = __fdiv_rn(1.0f, *tau_p);

    // per-lane base: even lane -> row 0 of each pair, odd lane -> row 1
    const float* __restrict__ xb = x   + (size_t)(odd ? 1 : 0) * bn + (size_t)q4 * 4;
    float* __restrict__ ob       = out + (size_t)(odd ? 1 : 0) * bn + (size_t)q4 * 4;
    const size_t ps = (size_t)2 * bn;      // pair stride (2 rows)

    // prologue: fill ring with pairs 0..PF-1
    f32x4 buf[PF];
#pragma unroll
    for (int k = 0; k < PF; ++k)
        buf[k] = __builtin_nontemporal_load(
            reinterpret_cast<const f32x4*>(xb + (size_t)k * ps));

    float v0 = 0.f, v1 = 0.f;   // the thread's two site chains

    for (int g = 0; g < NGRP; ++g) {
        const float* __restrict__ xg = xb + (size_t)(g + 1) * PF * ps;
        float* __restrict__ og       = ob + (size_t)g * PF * ps;
#pragma unroll
        for (int k = 0; k < PF; ++k) {
            const f32x4 V = buf[k];
            if (g + 1 < NGRP)
                buf[k] = __builtin_nontemporal_load(
                    reinterpret_cast<const f32x4*>(xg + (size_t)k * ps));

            // ---- input swap: even holds row r0 (.xy mine, .zw partner's),
            //      odd holds row r1 (.xy partner's, .zw mine).
            // even sends .zw (partner's r0), odd sends .xy (partner's r1).
            const float sx = odd ? V.x : V.z;
            const float sy = odd ? V.y : V.w;
            const float rx = __shfl_xor(sx, 1, 64);
            const float ry = __shfl_xor(sy, 1, 64);

            const float x0a = odd ? rx  : V.x;   // row r0, site a
            const float x0b = odd ? ry  : V.y;   // row r0, site b
            const float x1a = odd ? V.z : rx;    // row r1, site a
            const float x1b = odd ? V.w : ry;    // row r1, site b

            // ---- two sequential timesteps per site chain
            const StepOut a0 = pmlif_step(x0a, v0, inv_tau, v_th);
            const StepOut b0 = pmlif_step(x0b, v1, inv_tau, v_th);
            const StepOut a1 = pmlif_step(x1a, a0.v, inv_tau, v_th);
            const StepOut b1 = pmlif_step(x1b, b0.v, inv_tau, v_th);
            v0 = a1.v; v1 = b1.v;

            // ---- spike swap: even stores row r0 (needs odd's s0),
            //      odd stores row r1 (needs even's s1).
            const float tx = odd ? a0.s : a1.s;
            const float ty = odd ? b0.s : b1.s;
            const float ux = __shfl_xor(tx, 1, 64);
            const float uy = __shfl_xor(ty, 1, 64);

            f32x4 st;
            st.x = odd ? ux   : a0.s;
            st.y = odd ? uy   : b0.s;
            st.z = odd ? a1.s : ux;
            st.w = odd ? b1.s : uy;

            __builtin_nontemporal_store(
                st, reinterpret_cast<f32x4*>(og + (size_t)k * ps));
        }
    }
}

extern "C" void kernel_launch(void* const* d_in, const int* in_sizes, int n_in,
                              void* d_out, int out_size, void* d_ws, size_t ws_size,
                              hipStream_t stream) {
    const float* x    = (const float*)d_in[0];
    const float* v_th = (const float*)d_in[1];
    const float* tau  = (const float*)d_in[2];
    float* out = (float*)d_out;

    const int total = in_sizes[0];            // T * B * N
    const int bn    = total / T_STEPS;        // B * N (inner, contiguous)
    const int n2    = bn / 2;                 // f32x2 sites

    const int block = 256;
    const int grid  = (n2 + block - 1) / block;

    pmlif_scan_kernel<<<grid, block, 0, stream>>>(x, out, v_th, tau, bn);
}

// Round 12
// 103.017 us; speedup vs baseline: 1.1527x; 1.0104x over previous
//
#include <hip/hip_runtime.h>

// PmLIF membrane recurrence — R12: producer/consumer wave specialization.
//
// Mechanism under test: in the fused kernel, every load's vmcnt wait is
// queued behind interleaved stores and the recurrence periodically stalls
// prefetch ISSUE — the read stream is coupled to the compute chain. Here:
//   waves 0-1 (producers): stream x -> LDS, 16B/lane nt loads, NO recurrence
//     in their vmem queue (copy-like read stream).
//   waves 2-3 (consumers): ds_read_b128 from LDS, run the bit-exact chains,
//     fire-and-forget 16B nt spike stores (fill-like write stream).
// Double-buffered 4-row tiles; 1 __syncthreads per phase (16 phases);
// barrier latency overlaps across 8 independent blocks/CU.
//
// Arithmetic chain is byte-identical to R6 (bit-exact vs reference):
//   t = x - v ; h = v + inv_tau*t (rounded mul+add, no fma)
//   s = (h - v_th) > 0 ; v = s ? 0 : h
//
// Geometry: bn = B*N = 1048576 floats/row. Block owns 512 columns (f32):
//   consumers: 128 threads x f32x4 chain (4 sites each).
//   producers: 128 threads x one 16B chunk of the block's 2KB row-slice.
// LDS: 2 bufs x 4 rows x 2KB = 16KB/block; 8 blocks/CU -> 128KB <= 160KB.
// Grid: bn/512 = 2048 blocks x 256 thr -> 32 waves/CU.

constexpr int T_STEPS   = 64;
constexpr int ROWS_PH   = 4;                 // rows per phase
constexpr int NPHASE    = T_STEPS / ROWS_PH; // 16
constexpr int COLS_BLK  = 512;               // f32 columns per block
constexpr int CONS_THR  = 128;               // consumer threads (x4 sites)

typedef float f32x4 __attribute__((ext_vector_type(4)));

struct StepOut { float v; float s; };

__device__ __forceinline__ StepOut pmlif_step(float xv, float v,
                                              float inv_tau, float v_th) {
    const float t = __fsub_rn(xv, v);
    const float h = __fadd_rn(v, __fmul_rn(inv_tau, t));
    const float u = __fsub_rn(h, v_th);
    const bool  b = u > 0.0f;
    StepOut r;
    r.s = b ? 1.0f : 0.0f;
    r.v = b ? 0.0f : h;
    return r;
}

__global__ __launch_bounds__(256, 8) void pmlif_pc_kernel(
    const float* __restrict__ x,       // [T][bn]
    float* __restrict__ out,           // [T][bn]
    const float* __restrict__ v_th_p,
    const float* __restrict__ tau_p,
    int bn)
{
    __shared__ f32x4 lds[2][ROWS_PH][CONS_THR];   // 16 KB

    const int    tid      = threadIdx.x;
    const bool   producer = tid < 128;
    const size_t colbase  = (size_t)blockIdx.x * COLS_BLK;

    const float v_th    = *v_th_p;
    const float inv_tau = __fdiv_rn(1.0f, *tau_p);

    if (producer) {
        // ---- producer: thread i owns 16B chunk i of the block's row-slice
        const int i = tid;
        const float* __restrict__ gp = x + colbase + (size_t)i * 4;

        // prologue: rows 0..3 -> buf0
        {
            f32x4 a = __builtin_nontemporal_load((const f32x4*)(gp + (size_t)0 * bn));
            f32x4 b = __builtin_nontemporal_load((const f32x4*)(gp + (size_t)1 * bn));
            f32x4 c = __builtin_nontemporal_load((const f32x4*)(gp + (size_t)2 * bn));
            f32x4 d = __builtin_nontemporal_load((const f32x4*)(gp + (size_t)3 * bn));
            lds[0][0][i] = a; lds[0][1][i] = b; lds[0][2][i] = c; lds[0][3][i] = d;
        }
        __syncthreads();

        for (int p = 0; p < NPHASE; ++p) {
            if (p + 1 < NPHASE) {
                const float* __restrict__ gb = gp + (size_t)(p + 1) * ROWS_PH * bn;
                f32x4 a = __builtin_nontemporal_load((const f32x4*)(gb + (size_t)0 * bn));
                f32x4 b = __builtin_nontemporal_load((const f32x4*)(gb + (size_t)1 * bn));
                f32x4 c = __builtin_nontemporal_load((const f32x4*)(gb + (size_t)2 * bn));
                f32x4 d = __builtin_nontemporal_load((const f32x4*)(gb + (size_t)3 * bn));
                const int nb = (p + 1) & 1;
                lds[nb][0][i] = a; lds[nb][1][i] = b; lds[nb][2][i] = c; lds[nb][3][i] = d;
            }
            __syncthreads();
        }
    } else {
        // ---- consumer: thread j owns 4 adjacent sites (f32x4 chain)
        const int j = tid - 128;
        float* __restrict__ op = out + colbase + (size_t)j * 4;

        float va = 0.f, vb = 0.f, vc = 0.f, vd = 0.f;

        __syncthreads();   // matches producer prologue barrier

        for (int p = 0; p < NPHASE; ++p) {
            const int cb = p & 1;
#pragma unroll
            for (int r = 0; r < ROWS_PH; ++r) {
                const f32x4 xv = lds[cb][r][j];

                const StepOut s0 = pmlif_step(xv.x, va, inv_tau, v_th);
                const StepOut s1 = pmlif_step(xv.y, vb, inv_tau, v_th);
                const StepOut s2 = pmlif_step(xv.z, vc, inv_tau, v_th);
                const StepOut s3 = pmlif_step(xv.w, vd, inv_tau, v_th);
                va = s0.v; vb = s1.v; vc = s2.v; vd = s3.v;

                f32x4 s;
                s.x = s0.s; s.y = s1.s; s.z = s2.s; s.w = s3.s;
                __builtin_nontemporal_store(
                    s, (f32x4*)(op + (size_t)(p * ROWS_PH + r) * bn));
            }
            __syncthreads();
        }
    }
}

extern "C" void kernel_launch(void* const* d_in, const int* in_sizes, int n_in,
                              void* d_out, int out_size, void* d_ws, size_t ws_size,
                              hipStream_t stream) {
    const float* x    = (const float*)d_in[0];
    const float* v_th = (const float*)d_in[1];
    const float* tau  = (const float*)d_in[2];
    float* out = (float*)d_out;

    const int total = in_sizes[0];            // T * B * N
    const int bn    = total / T_STEPS;        // B * N (inner, contiguous)

    const int block = 256;
    const int grid  = bn / COLS_BLK;          // 2048 for bn = 1048576

    pmlif_pc_kernel<<<grid, block, 0, stream>>>(x, out, v_th, tau, bn);
}